// Round 7
// baseline (736.536 us; speedup 1.0000x reference)
//
#include <hip/hip_runtime.h>

#define HIDDEN 51
#define LSEQ 1000
#define NK 26   // k-columns per wave: wave0 k=0..25, wave1 k=26..51 (51 = zero pad)

// Branch-free tanh: tanh(v) = 1 - 2/(exp2(2*log2e*v)+1). Saturates to +/-1.
__device__ __forceinline__ float fast_tanh(float v) {
    float e = __builtin_amdgcn_exp2f(v * 2.885390081777927f);  // 2*log2(e)
    float r = __builtin_amdgcn_rcpf(e + 1.0f);
    return fmaf(-2.0f, r, 1.0f);
}

// Two waves per batch element, k-split (26 U-columns x 4 gates = 104 regs/wave).
// Both waves hold bitwise-identical h/c (gate = own + other partial; float add
// commutes), so each wave broadcasts h from its OWN register via v_readlane
// with COMPILE-TIME-CONSTANT lane indices (R5 lesson: tid-derived index isn't
// provably uniform -> waterfall). Role split via scalar branch on
// readfirstlane(wid) with the FMA block cloned so indices are literals.
// Per-step LDS: one ds_write_b128 + one barrier + one ds_read_b128 (parity
// double-buffered). Output dot runs one step behind on wave1.
//
// __launch_bounds__(128,1): R6 lesson -- with min-2-waves/EU the unified-file
// allocator capped at 256 regs and pushed U[26][4] into AGPRs (VGPR_Count=68),
// paying ~104 v_accvgpr_read per step (~40% of all VALU issue). A 512-reg
// budget lets U live in arch VGPRs; true demand ~180 regs still gives
// 2 waves/SIMD at runtime.
__global__ __launch_bounds__(128, 1) void lstm_seq_kernel(
    const float* __restrict__ x,
    const float* __restrict__ W_w,
    const float* __restrict__ W_b,
    const float* __restrict__ U_w,
    const float* __restrict__ U_b,
    const float* __restrict__ lin_w,
    const float* __restrict__ lin_b,
    float* __restrict__ out)
{
    __shared__ float pg[2][2][64][4];    // [t&1][wid][lane][gate] exchange

    const int b    = blockIdx.x;
    const int tid  = threadIdx.x;
    const int wid  = tid >> 6;           // 0 or 1
    const int lane = tid & 63;
    const bool active = lane < HIDDEN;   // lanes 51..63 produce exact zeros
    const int m = active ? lane : 0;

    // Scalar-uniform wave id (SGPR) -> s_cmp/s_cbranch, no exec masking.
    const int swid = __builtin_amdgcn_readfirstlane(wid);

    // x-projection + fused bias, carried by wave0 only (counted once).
    float ww[4], bb[4];
#pragma unroll
    for (int g = 0; g < 4; ++g) {
        const int row = m + g * HIDDEN;
        ww[g] = (active && swid == 0) ? W_w[row] : 0.f;
        bb[g] = (active && swid == 0) ? (W_b[row] + U_b[row]) : 0.f;
    }
    // Output dot weights live on wave1 (the butterfly wave).
    const float lw = (active && swid == 1) ? lin_w[m] : 0.f;
    const float lb = lin_b[0];

    // U columns for this wave: k = swid*NK + j. k==51 zero-padded. Inactive
    // lanes zero their rows so their h stays exactly 0 -> readlane(h,51)==0.
    float U[NK][4];
#pragma unroll
    for (int j = 0; j < NK; ++j) {
        const int k = swid * NK + j;
#pragma unroll
        for (int g = 0; g < 4; ++g) {
            const int row = m + g * HIDDEN;
            U[j][g] = (active && k < HIDDEN) ? U_w[row * HIDDEN + k] : 0.f;
        }
    }

    float h = 0.f, c = 0.f, red = 0.f;
    const float* __restrict__ xrow = x + (long)b * LSEQ;
    float* __restrict__ orow = out + (long)b * LSEQ;

    float x_cur = (swid == 0) ? xrow[0] : 0.f;  // only wave0 touches x
    for (int t = 0; t < LSEQ; ++t) {
        const int par = t & 1;
        float x_next = x_cur;
        float p0, p1, p2, p3;
        float r = red;

        if (swid == 0) {
            // ---- wave0: x-term + k = 0..25 (constant readlane indices) ----
            const int tn = (t + 1 < LSEQ) ? (t + 1) : t;
            x_next = xrow[tn];
            p0 = fmaf(x_cur, ww[0], bb[0]);
            p1 = fmaf(x_cur, ww[1], bb[1]);
            p2 = fmaf(x_cur, ww[2], bb[2]);
            p3 = fmaf(x_cur, ww[3], bb[3]);
#pragma unroll
            for (int j = 0; j < NK; ++j) {
                const float hk = __builtin_bit_cast(
                    float,
                    __builtin_amdgcn_readlane(__builtin_bit_cast(int, h), j));
                p0 = fmaf(hk, U[j][0], p0);
                p1 = fmaf(hk, U[j][1], p1);
                p2 = fmaf(hk, U[j][2], p2);
                p3 = fmaf(hk, U[j][3], p3);
            }
        } else {
            // ---- wave1: pipelined output butterfly + k = 26..51 ----
            p0 = p1 = p2 = p3 = 0.f;
#pragma unroll
            for (int off = 32; off > 0; off >>= 1)
                r += __shfl_xor(r, off, 64);
#pragma unroll
            for (int j = 0; j < NK; ++j) {
                const float hk = __builtin_bit_cast(
                    float,
                    __builtin_amdgcn_readlane(__builtin_bit_cast(int, h),
                                              NK + j));  // literal 26..51
                p0 = fmaf(hk, U[j][0], p0);
                p1 = fmaf(hk, U[j][1], p1);
                p2 = fmaf(hk, U[j][2], p2);
                p3 = fmaf(hk, U[j][3], p3);
            }
            // Store previous step's output (lane 0), before the barrier so
            // the store issues early; nothing waits on it.
            const int ot = (t > 0) ? (t - 1) : 0;
            if (lane == 0) orow[ot] = r + lb;
        }

        // Exchange partials: one b128 each way, ONE barrier, parity-buffered.
        *(float4*)&pg[par][wid][lane][0] = make_float4(p0, p1, p2, p3);
        __syncthreads();
        const float4 po = *(const float4*)&pg[par][1 - wid][lane][0];

        // own + other commutes exactly -> bitwise-identical on both waves.
        const float gi = p0 + po.x;
        const float gf = p1 + po.y;
        const float gg = p2 + po.z;
        const float go = p3 + po.w;

        // NOTE: faithful to reference -- no sigmoid on gates.
        c = fmaf(gf, c, gi * gg);
        const float th = fast_tanh(c);
        h = go * th;
        red = h * lw;

        x_cur = x_next;
    }

    // Drain: output for t = LSEQ-1 (meaningful only on wave1; wave0's lw=0).
#pragma unroll
    for (int off = 32; off > 0; off >>= 1)
        red += __shfl_xor(red, off, 64);
    if (tid == 64) orow[LSEQ - 1] = red + lb;
}

extern "C" void kernel_launch(void* const* d_in, const int* in_sizes, int n_in,
                              void* d_out, int out_size, void* d_ws, size_t ws_size,
                              hipStream_t stream) {
    const float* x     = (const float*)d_in[0];
    const float* W_w   = (const float*)d_in[1];
    const float* W_b   = (const float*)d_in[2];
    const float* U_w   = (const float*)d_in[3];
    const float* U_b   = (const float*)d_in[4];
    const float* lin_w = (const float*)d_in[5];
    const float* lin_b = (const float*)d_in[6];
    // d_in[7] = future (static 0; out_size == B*LSEQ)
    float* out = (float*)d_out;

    const int B = in_sizes[0] / LSEQ;  // 1024
    lstm_seq_kernel<<<dim3(B), dim3(128), 0, stream>>>(
        x, W_w, W_b, U_w, U_b, lin_w, lin_b, out);
}

// Round 8
// 537.317 us; speedup vs baseline: 1.3708x; 1.3708x over previous
//
#include <hip/hip_runtime.h>

#define HIDDEN 51
#define LSEQ 1000
#define UNROLL 8    // steps buffered between butterfly/store groups

typedef float v2f __attribute__((ext_vector_type(2)));

// Branch-free tanh: tanh(v) = 1 - 2/(exp2(2*log2e*v)+1). Saturates to +/-1.
__device__ __forceinline__ float fast_tanh(float v) {
    float e = __builtin_amdgcn_exp2f(v * 2.885390081777927f);  // 2*log2(e)
    float r = __builtin_amdgcn_rcpf(e + 1.0f);
    return fmaf(-2.0f, r, 1.0f);
}

// One wave per batch element, no barriers. Evidence-driven design:
//  - h broadcast through a per-block LDS buffer (R4-style): hk lands in a
//    VGPR, so FMAs can source U from AGPRs directly. (R2/R5/R7 readlane
//    variants put hk in an SGPR; SGPR+AGPR in one VALU op is illegal, so the
//    compiler emitted one v_accvgpr_read per U element -- the persistent
//    ~110-instr/step excess across those rounds.)
//  - k-dimension paired for v_pk_fma_f32: hk2={h_2j,h_2j+1} comes straight
//    from the float4 LDS broadcast (no packing movs), U is float2[4][26].
//    204 scalar FMA -> 104 packed = half the FMA issue.
//  - Output projection hoisted: 8 steps of h*lw buffered in registers
//    (unroll-by-8 keeps indices compile-time -- R3 lesson), then 8
//    independent butterflies (latencies overlap) + one lane0 float4 x2
//    store per group. No per-step serial swizzle chain.
__global__ __launch_bounds__(64, 1) void lstm_seq_kernel(
    const float* __restrict__ x,
    const float* __restrict__ W_w,
    const float* __restrict__ W_b,
    const float* __restrict__ U_w,
    const float* __restrict__ U_b,
    const float* __restrict__ lin_w,
    const float* __restrict__ lin_b,
    float* __restrict__ out)
{
    __shared__ __attribute__((aligned(16))) float hb[64];  // h broadcast

    const int b    = blockIdx.x;
    const int lane = threadIdx.x;        // 0..63
    const bool active = lane < HIDDEN;   // lanes 51..63 produce exact zeros
    const int m = active ? lane : 0;

    float ww[4], bb[4];
#pragma unroll
    for (int g = 0; g < 4; ++g) {
        const int row = m + g * HIDDEN;
        ww[g] = active ? W_w[row] : 0.f;
        bb[g] = active ? (W_b[row] + U_b[row]) : 0.f;
    }
    const float lw = active ? lin_w[m] : 0.f;
    const float lb = lin_b[0];

    // U packed over k-pairs: Up[g][j] = {U[row][2j], U[row][2j+1]}, j<26.
    // k==51 is a zero pad (matches hb[51]==0 from lane 51's h==0).
    v2f Up[4][26];
#pragma unroll
    for (int j = 0; j < 26; ++j) {
        const int k0 = 2 * j, k1 = 2 * j + 1;
#pragma unroll
        for (int g = 0; g < 4; ++g) {
            const int row = m + g * HIDDEN;
            v2f u;
            u.x = (active && k0 < HIDDEN) ? U_w[row * HIDDEN + k0] : 0.f;
            u.y = (active && k1 < HIDDEN) ? U_w[row * HIDDEN + k1] : 0.f;
            Up[g][j] = u;
        }
    }

    float h = 0.f, c = 0.f;
    const float* __restrict__ xrow = x + (long)b * LSEQ;
    float* __restrict__ orow = out + (long)b * LSEQ;

    hb[lane] = 0.f;                       // single wave: in-order LDS pipe
    __builtin_amdgcn_wave_barrier();      // compile-time ordering insurance

    for (int T = 0; T < LSEQ; T += UNROLL) {
        float xg[UNROLL], rb[UNROLL];
#pragma unroll
        for (int s = 0; s < UNROLL; ++s) xg[s] = xrow[T + s];  // uniform

#pragma unroll
        for (int s = 0; s < UNROLL; ++s) {
            v2f a0 = {0.f, 0.f}, a1 = {0.f, 0.f};
            v2f a2 = {0.f, 0.f}, a3 = {0.f, 0.f};
#pragma unroll
            for (int q = 0; q < 13; ++q) {
                // Same-address b128 broadcast: conflict-free, hk in VGPRs.
                const float4 hv = *(const float4*)&hb[q * 4];
                const v2f hlo = {hv.x, hv.y};
                const v2f hhi = {hv.z, hv.w};
                a0 = __builtin_elementwise_fma(hlo, Up[0][2 * q], a0);
                a1 = __builtin_elementwise_fma(hlo, Up[1][2 * q], a1);
                a2 = __builtin_elementwise_fma(hlo, Up[2][2 * q], a2);
                a3 = __builtin_elementwise_fma(hlo, Up[3][2 * q], a3);
                a0 = __builtin_elementwise_fma(hhi, Up[0][2 * q + 1], a0);
                a1 = __builtin_elementwise_fma(hhi, Up[1][2 * q + 1], a1);
                a2 = __builtin_elementwise_fma(hhi, Up[2][2 * q + 1], a2);
                a3 = __builtin_elementwise_fma(hhi, Up[3][2 * q + 1], a3);
            }
            const float gi = a0.x + a0.y + fmaf(xg[s], ww[0], bb[0]);
            const float gf = a1.x + a1.y + fmaf(xg[s], ww[1], bb[1]);
            const float gg = a2.x + a2.y + fmaf(xg[s], ww[2], bb[2]);
            const float go = a3.x + a3.y + fmaf(xg[s], ww[3], bb[3]);

            // NOTE: faithful to reference -- no sigmoid on gates.
            c = fmaf(gf, c, gi * gg);
            h = go * fast_tanh(c);        // inactive lanes stay exactly 0
            rb[s] = h * lw;

            __builtin_amdgcn_wave_barrier();  // reads above precede write
            hb[lane] = h;
            __builtin_amdgcn_wave_barrier();  // write precedes next reads
        }

        // 8 independent butterflies -- swizzle latencies overlap across s.
#pragma unroll
        for (int s = 0; s < UNROLL; ++s) {
#pragma unroll
            for (int off = 32; off > 0; off >>= 1)
                rb[s] += __shfl_xor(rb[s], off, 64);
        }
        if (lane == 0) {
            float4 o0 = {rb[0] + lb, rb[1] + lb, rb[2] + lb, rb[3] + lb};
            float4 o1 = {rb[4] + lb, rb[5] + lb, rb[6] + lb, rb[7] + lb};
            *(float4*)&orow[T]     = o0;   // orow 16B-aligned (b*4000 bytes)
            *(float4*)&orow[T + 4] = o1;
        }
    }
}

extern "C" void kernel_launch(void* const* d_in, const int* in_sizes, int n_in,
                              void* d_out, int out_size, void* d_ws, size_t ws_size,
                              hipStream_t stream) {
    const float* x     = (const float*)d_in[0];
    const float* W_w   = (const float*)d_in[1];
    const float* W_b   = (const float*)d_in[2];
    const float* U_w   = (const float*)d_in[3];
    const float* U_b   = (const float*)d_in[4];
    const float* lin_w = (const float*)d_in[5];
    const float* lin_b = (const float*)d_in[6];
    // d_in[7] = future (static 0; out_size == B*LSEQ)
    float* out = (float*)d_out;

    const int B = in_sizes[0] / LSEQ;  // 1024
    lstm_seq_kernel<<<dim3(B), dim3(64), 0, stream>>>(
        x, W_w, W_b, U_w, U_b, lin_w, lin_b, out);
}